// Round 2
// baseline (362.709 us; speedup 1.0000x reference)
//
#include <hip/hip_runtime.h>
#include <stdint.h>

// ---------------- types ----------------
typedef _Float16 f16x8 __attribute__((ext_vector_type(8)));
typedef float    f32x16 __attribute__((ext_vector_type(16)));

union Frag {
  f16x8    v;
  uint32_t w[4];
  _Float16 h[8];
};

__device__ __forceinline__ uint32_t pack2h(float a, float b) {
  union { _Float16 h[2]; uint32_t u; } r;
  r.h[0] = (_Float16)a;   // RNE f32->f16
  r.h[1] = (_Float16)b;
  return r.u;
}

__device__ __forceinline__ void g2lds16(const void* g, void* l) {
  __builtin_amdgcn_global_load_lds(
      (const __attribute__((address_space(1))) uint32_t*)g,
      (__attribute__((address_space(3))) uint32_t*)l, 16, 0, 0);
}

// ---------------- prep: fragment-order the weights (f16) ----------------
// ws layout (bytes):
//   wfrag  @ 0      : [9][4 ot][8 kt][64 lane][8 j] f16  = 294912 B
//   w0frag @ 294912 : [4 ot][64 lane][8 j]          f16  = 4096 B   (K padded 4->16)
//   biasws @ 299008 : [10][128]                     f32  = 5120 B   (b0 then bh[0..8])
//   woutf  @ 304128 : [8 kt][64 lane][8 j]          f32  = 16384 B
// fragment value convention (32x32x16 f16 MFMA):
//   A lane l holds row i = l&31, k = (l>>5)*8 + j
//   B lane l holds col j = l&31, k = (l>>5)*8 + j
//   D lane l holds col = l&31, row = (r&3) + 8*(r>>2) + 4*(l>>5)
__global__ void prep_kernel(const float* __restrict__ W0, const float* __restrict__ b0,
                            const float* __restrict__ Wh, const float* __restrict__ bh,
                            const float* __restrict__ Wout,
                            _Float16* __restrict__ wfrag, _Float16* __restrict__ w0frag,
                            float* __restrict__ biasws, float* __restrict__ woutf) {
  const int stride = gridDim.x * blockDim.x;
  for (int idx = blockIdx.x * blockDim.x + threadIdx.x; idx < 154880; idx += stride) {
    if (idx < 147456) {                       // wfrag: Wh[l][o][k] -> A-fragment order
      const int j = idx & 7, lane = (idx >> 3) & 63, kt = (idx >> 9) & 7,
                ot = (idx >> 12) & 3, l = idx >> 14;
      const int o = ot * 32 + (lane & 31);
      const int k = kt * 16 + (lane >> 5) * 8 + j;
      wfrag[idx] = (_Float16)Wh[(l * 128 + o) * 128 + k];
    } else if (idx < 147456 + 2048) {         // w0frag (K padded with zeros)
      const int i = idx - 147456;
      const int j = i & 7, lane = (i >> 3) & 63, ot = i >> 9;
      const int o = ot * 32 + (lane & 31);
      const int k = (lane >> 5) * 8 + j;
      w0frag[i] = (_Float16)(k < 4 ? W0[o * 4 + k] : 0.0f);
    } else if (idx < 147456 + 2048 + 1280) {  // biases, f32, [layer][o]
      const int i = idx - (147456 + 2048);
      const int l = i >> 7, c = i & 127;
      biasws[i] = (l == 0) ? b0[c] : bh[(l - 1) * 128 + c];
    } else {                                  // Wout in B-frag k-order, f32
      const int i = idx - (147456 + 2048 + 1280);
      const int j = i & 7, lane = (i >> 3) & 63, kt = i >> 9;
      const int k = kt * 16 + (lane >> 5) * 8 + j;
      woutf[i] = Wout[k];
    }
  }
}

// ---------------- fused MLP ----------------
__global__ __launch_bounds__(256, 2) void mlp_fused(
    const float* __restrict__ x,
    const _Float16* __restrict__ wfrag,
    const _Float16* __restrict__ w0frag,
    const float* __restrict__ biasws,
    const float* __restrict__ woutf,
    const float* __restrict__ boutp,
    float* __restrict__ out) {
  // 2 x 32 KB W double-buffer + all biases; 70.7 KB -> 2 blocks/CU
  __shared__ __align__(16) unsigned char ldsW[2][32768];
  __shared__ __align__(16) float ldsBias[1280];

  const int t    = threadIdx.x;
  const int lane = t & 63;
  const int wv   = t >> 6;
  const int h    = lane >> 5;   // half-wave
  const int ln   = lane & 31;
  const long rowbase = (long)blockIdx.x * 256 + wv * 64;  // + nt*32 + ln

  // ---- prologue staging: W[1] -> ldsW[0]; all biases -> ldsBias ----
  {
    const unsigned char* src = (const unsigned char*)wfrag;  // layer 1 at offset 0
#pragma unroll
    for (int i = 0; i < 8; ++i) {
      const int off = i * 4096 + t * 16;
      g2lds16(src + off, &ldsW[0][off]);
    }
    const unsigned char* bsrc = (const unsigned char*)biasws;
    g2lds16(bsrc + t * 16, (unsigned char*)ldsBias + t * 16);            // chunks 0..255
    if (t < 64) g2lds16(bsrc + (256 + t) * 16, (unsigned char*)ldsBias + (256 + t) * 16);
  }

  Frag   B[2][8];      // current-layer input fragments (H^T), per nt / k-tile
  f32x16 acc[4][2];    // [o-tile][n-tile], D = H_out^T
  const f32x16 fzero = (f32x16)0.0f;

  // ---- layer 0: K=16 zero-padded MFMA straight from global ----
  {
    Frag xb[2];
#pragma unroll
    for (int nt = 0; nt < 2; ++nt) {
      float4 xv = make_float4(0.f, 0.f, 0.f, 0.f);
      if (h == 0) xv = *(const float4*)(x + (rowbase + nt * 32 + ln) * 4);
      xb[nt].w[0] = pack2h(xv.x, xv.y);
      xb[nt].w[1] = pack2h(xv.z, xv.w);
      xb[nt].w[2] = 0u;
      xb[nt].w[3] = 0u;
    }
#pragma unroll
    for (int ot = 0; ot < 4; ++ot) {
      const f16x8 a0 = *(const f16x8*)(w0frag + ot * 512 + lane * 8);
      acc[ot][0] = __builtin_amdgcn_mfma_f32_32x32x16_f16(a0, xb[0].v, fzero, 0, 0, 0);
      acc[ot][1] = __builtin_amdgcn_mfma_f32_32x32x16_f16(a0, xb[1].v, fzero, 0, 0, 0);
    }
  }

  // epilogue: bias+relu, pack to f16, exchange lane<->lane+32 halves so each
  // lane ends up holding its row's k-slice in next-layer B-fragment order.
  auto do_epilogue = [&](int l) {
    const float* biaslds = ldsBias + l * 128;
#pragma unroll
    for (int ot = 0; ot < 4; ++ot) {
      float4 bb[4];
#pragma unroll
      for (int g = 0; g < 4; ++g)
        bb[g] = *(const float4*)(biaslds + ot * 32 + g * 8 + h * 4);
#pragma unroll
      for (int nt = 0; nt < 2; ++nt) {
        uint32_t P[4][2];
#pragma unroll
        for (int g = 0; g < 4; ++g) {
#pragma unroll
          for (int c = 0; c < 2; ++c) {
            const float v0 = fmaxf(acc[ot][nt][g * 4 + c * 2 + 0] + bb[g][c * 2 + 0], 0.f);
            const float v1 = fmaxf(acc[ot][nt][g * 4 + c * 2 + 1] + bb[g][c * 2 + 1], 0.f);
            P[g][c] = pack2h(v0, v1);
          }
        }
#pragma unroll
        for (int u = 0; u < 2; ++u) {
          const uint32_t a0s = (uint32_t)__shfl_xor((int)P[2 * u][0], 32, 64);
          const uint32_t a1s = (uint32_t)__shfl_xor((int)P[2 * u][1], 32, 64);
          const uint32_t b0s = (uint32_t)__shfl_xor((int)P[2 * u + 1][0], 32, 64);
          const uint32_t b1s = (uint32_t)__shfl_xor((int)P[2 * u + 1][1], 32, 64);
          Frag nb;
          nb.w[0] = h ? b0s : P[2 * u][0];
          nb.w[1] = h ? b1s : P[2 * u][1];
          nb.w[2] = h ? P[2 * u + 1][0] : a0s;
          nb.w[3] = h ? P[2 * u + 1][1] : a1s;
          B[nt][ot * 2 + u] = nb;
        }
      }
    }
  };

  __asm__ volatile("s_waitcnt vmcnt(0)" ::: "memory");  // W1 + biases staged (this wave)
  __syncthreads();                                      // ... and all waves
  do_epilogue(0);

  // ---- 9 hidden layers ----
#pragma unroll 1
  for (int l = 1; l <= 9; ++l) {
    const int cur = (l - 1) & 1;
    const int nxt = l & 1;
    if (l < 9) {  // prefetch W[l+1] into the other buffer
      const unsigned char* src = (const unsigned char*)wfrag + (size_t)l * 32768;
#pragma unroll
      for (int i = 0; i < 8; ++i) {
        const int off = i * 4096 + t * 16;
        g2lds16(src + off, &ldsW[nxt][off]);
      }
    }
    const unsigned char* wl = &ldsW[cur][0];
#pragma unroll
    for (int kt = 0; kt < 8; ++kt) {
#pragma unroll
      for (int ot = 0; ot < 4; ++ot) {
        const f16x8 a = *(const f16x8*)(wl + ot * 8192 + kt * 1024 + lane * 16);
        if (kt == 0) {
          acc[ot][0] = __builtin_amdgcn_mfma_f32_32x32x16_f16(a, B[0][kt].v, fzero, 0, 0, 0);
          acc[ot][1] = __builtin_amdgcn_mfma_f32_32x32x16_f16(a, B[1][kt].v, fzero, 0, 0, 0);
        } else {
          acc[ot][0] = __builtin_amdgcn_mfma_f32_32x32x16_f16(a, B[0][kt].v, acc[ot][0], 0, 0, 0);
          acc[ot][1] = __builtin_amdgcn_mfma_f32_32x32x16_f16(a, B[1][kt].v, acc[ot][1], 0, 0, 0);
        }
      }
    }
    do_epilogue(l);
    if (l < 9) {
      __asm__ volatile("s_waitcnt vmcnt(0)" ::: "memory");
      __syncthreads();
    }
  }

  // ---- output layer: VALU dot over the register-resident row ----
  const float boutv = *boutp;
#pragma unroll
  for (int nt = 0; nt < 2; ++nt) {
    float p = 0.f;
#pragma unroll
    for (int kt = 0; kt < 8; ++kt) {
      const float4 wa = *(const float4*)(woutf + (kt * 64 + lane) * 8);
      const float4 wb = *(const float4*)(woutf + (kt * 64 + lane) * 8 + 4);
      p += (float)B[nt][kt].h[0] * wa.x;
      p += (float)B[nt][kt].h[1] * wa.y;
      p += (float)B[nt][kt].h[2] * wa.z;
      p += (float)B[nt][kt].h[3] * wa.w;
      p += (float)B[nt][kt].h[4] * wb.x;
      p += (float)B[nt][kt].h[5] * wb.y;
      p += (float)B[nt][kt].h[6] * wb.z;
      p += (float)B[nt][kt].h[7] * wb.w;
    }
    p += __shfl_xor(p, 32, 64);
    if (h == 0) out[rowbase + nt * 32 + ln] = p + boutv;
  }
}

extern "C" void kernel_launch(void* const* d_in, const int* in_sizes, int n_in,
                              void* d_out, int out_size, void* d_ws, size_t ws_size,
                              hipStream_t stream) {
  (void)n_in; (void)out_size; (void)ws_size;  // needs ~321 KB of ws
  const float* x    = (const float*)d_in[0];
  const float* W0   = (const float*)d_in[1];
  const float* b0   = (const float*)d_in[2];
  const float* Wh   = (const float*)d_in[3];
  const float* bh   = (const float*)d_in[4];
  const float* Wout = (const float*)d_in[5];
  const float* bout = (const float*)d_in[6];
  float* out = (float*)d_out;

  char* ws = (char*)d_ws;
  _Float16* wfrag  = (_Float16*)(ws);
  _Float16* w0frag = (_Float16*)(ws + 294912);
  float*    biasws = (float*)(ws + 299008);
  float*    woutf  = (float*)(ws + 304128);

  const int n = in_sizes[0] / 4;  // 1048576 points

  prep_kernel<<<dim3(160), dim3(256), 0, stream>>>(W0, b0, Wh, bh, Wout,
                                                   wfrag, w0frag, biasws, woutf);
  mlp_fused<<<dim3(n / 256), dim3(256), 0, stream>>>(x, wfrag, w0frag, biasws,
                                                     woutf, bout, out);
}

// Round 4
// 280.448 us; speedup vs baseline: 1.2933x; 1.2933x over previous
//
#include <hip/hip_runtime.h>
#include <stdint.h>

// ---------------- types ----------------
typedef _Float16 f16x8 __attribute__((ext_vector_type(8)));
typedef __fp16   fp16x2 __attribute__((ext_vector_type(2)));
typedef float    f32x16 __attribute__((ext_vector_type(16)));

union Frag {
  f16x8    v;
  uint32_t w[4];
  _Float16 h[8];
};

__device__ __forceinline__ uint32_t pack2h(float a, float b) {
  union { _Float16 h[2]; uint32_t u; } r;
  r.h[0] = (_Float16)a;   // RNE f32->f16
  r.h[1] = (_Float16)b;
  return r.u;
}

__device__ __forceinline__ uint32_t pkrtz(float a, float b) {
  union { fp16x2 h2; uint32_t u; } cv;
  cv.h2 = __builtin_amdgcn_cvt_pkrtz(a, b);
  return cv.u;
}

__device__ __forceinline__ void g2lds16(const void* g, void* l) {
  __builtin_amdgcn_global_load_lds(
      (const __attribute__((address_space(1))) uint32_t*)g,
      (__attribute__((address_space(3))) uint32_t*)l, 16, 0, 0);
}

// ---------------- prep: fragment-order the weights (f16) ----------------
// ws layout (bytes):
//   wfrag   @ 0      : [9][4 ot][8 kt][64 lane][8 j] f16  = 294912 B
//   w0frag  @ 294912 : [4 ot][64 lane][8 j]          f16  = 4096 B   (K padded 4->16)
//   biasws  @ 299008 : [10][128]                     f32  = 5120 B   (b0 then bh[0..8])
//   woutf16 @ 304128 : [8 kt][64 lane][8 j]          f16  = 8192 B   (A-frag, rows!=0 zeroed)
// fragment value convention (32x32x16 f16 MFMA):
//   A lane l holds row i = l&31, k = (l>>5)*8 + j
//   B lane l holds col j = l&31, k = (l>>5)*8 + j
//   D lane l holds col = l&31, row = (r&3) + 8*(r>>2) + 4*(l>>5)
__global__ void prep_kernel(const float* __restrict__ W0, const float* __restrict__ b0,
                            const float* __restrict__ Wh, const float* __restrict__ bh,
                            const float* __restrict__ Wout,
                            _Float16* __restrict__ wfrag, _Float16* __restrict__ w0frag,
                            float* __restrict__ biasws, _Float16* __restrict__ woutf16) {
  const int stride = gridDim.x * blockDim.x;
  for (int idx = blockIdx.x * blockDim.x + threadIdx.x; idx < 154880; idx += stride) {
    if (idx < 147456) {                       // wfrag: Wh[l][o][k] -> A-fragment order
      const int j = idx & 7, lane = (idx >> 3) & 63, kt = (idx >> 9) & 7,
                ot = (idx >> 12) & 3, l = idx >> 14;
      const int o = ot * 32 + (lane & 31);
      const int k = kt * 16 + (lane >> 5) * 8 + j;
      wfrag[idx] = (_Float16)Wh[(l * 128 + o) * 128 + k];
    } else if (idx < 147456 + 2048) {         // w0frag (K padded with zeros)
      const int i = idx - 147456;
      const int j = i & 7, lane = (i >> 3) & 63, ot = i >> 9;
      const int o = ot * 32 + (lane & 31);
      const int k = (lane >> 5) * 8 + j;
      w0frag[i] = (_Float16)(k < 4 ? W0[o * 4 + k] : 0.0f);
    } else if (idx < 147456 + 2048 + 1280) {  // biases, f32, [layer][o]
      const int i = idx - (147456 + 2048);
      const int l = i >> 7, c = i & 127;
      biasws[i] = (l == 0) ? b0[c] : bh[(l - 1) * 128 + c];
    } else {                                  // Wout as masked A-fragment (row 0 only), f16
      const int i = idx - (147456 + 2048 + 1280);
      const int j = i & 7, lane = (i >> 3) & 63, kt = i >> 9;
      const int k = kt * 16 + (lane >> 5) * 8 + j;
      woutf16[i] = ((lane & 31) == 0) ? (_Float16)Wout[k] : (_Float16)0.0f;
    }
  }
}

// ---------------- fused MLP ----------------
__global__ __launch_bounds__(256, 2) void mlp_fused(
    const float* __restrict__ x,
    const _Float16* __restrict__ wfrag,
    const _Float16* __restrict__ w0frag,
    const float* __restrict__ biasws,
    const _Float16* __restrict__ woutf16,
    const float* __restrict__ boutp,
    float* __restrict__ out) {
  // 2 x 32 KB W double-buffer + all biases; 70.7 KB -> 2 blocks/CU
  __shared__ __align__(16) unsigned char ldsW[2][32768];
  __shared__ __align__(16) float ldsBias[1280];

  const int t    = threadIdx.x;
  const int lane = t & 63;
  const int wv   = t >> 6;
  const int h    = lane >> 5;   // half-wave
  const int ln   = lane & 31;
  const long rowbase = (long)blockIdx.x * 256 + wv * 64;  // + nt*32 + ln

  // ---- prologue staging: W[1] -> ldsW[0]; all biases -> ldsBias ----
  {
    const unsigned char* src = (const unsigned char*)wfrag;  // layer 1 at offset 0
#pragma unroll
    for (int i = 0; i < 8; ++i) {
      const int off = i * 4096 + t * 16;
      g2lds16(src + off, &ldsW[0][off]);
    }
    const unsigned char* bsrc = (const unsigned char*)biasws;
    g2lds16(bsrc + t * 16, (unsigned char*)ldsBias + t * 16);            // chunks 0..255
    if (t < 64) g2lds16(bsrc + (256 + t) * 16, (unsigned char*)ldsBias + (256 + t) * 16);
  }

  Frag   B[2][8];      // current-layer input fragments (H^T), per nt / k-tile
  f32x16 acc[4][2];    // [o-tile][n-tile], D = H_out^T
  const f32x16 fzero = (f32x16)0.0f;

  // ---- layer 0: K=16 zero-padded MFMA straight from global ----
  {
    Frag xb[2];
#pragma unroll
    for (int nt = 0; nt < 2; ++nt) {
      float4 xv = make_float4(0.f, 0.f, 0.f, 0.f);
      if (h == 0) xv = *(const float4*)(x + (rowbase + nt * 32 + ln) * 4);
      xb[nt].w[0] = pack2h(xv.x, xv.y);
      xb[nt].w[1] = pack2h(xv.z, xv.w);
      xb[nt].w[2] = 0u;
      xb[nt].w[3] = 0u;
    }
#pragma unroll
    for (int ot = 0; ot < 4; ++ot) {
      const f16x8 a0 = *(const f16x8*)(w0frag + ot * 512 + lane * 8);
      acc[ot][0] = __builtin_amdgcn_mfma_f32_32x32x16_f16(a0, xb[0].v, fzero, 0, 0, 0);
      acc[ot][1] = __builtin_amdgcn_mfma_f32_32x32x16_f16(a0, xb[1].v, fzero, 0, 0, 0);
    }
  }

  // epilogue: bias+relu, pack to f16 (RTZ), exchange lane<->lane+32 halves via
  // v_permlane32_swap_b32 so each lane holds its row's k-slice in next-layer
  // B-fragment order. One swap yields BOTH w[lo] and w[hi].
  auto do_epilogue = [&](int l) {
    const float* biaslds = ldsBias + l * 128;
#pragma unroll
    for (int ot = 0; ot < 4; ++ot) {
      float4 bb[4];
#pragma unroll
      for (int g = 0; g < 4; ++g)
        bb[g] = *(const float4*)(biaslds + ot * 32 + g * 8 + h * 4);
#pragma unroll
      for (int nt = 0; nt < 2; ++nt) {
        uint32_t P[4][2];
#pragma unroll
        for (int g = 0; g < 4; ++g) {
#pragma unroll
          for (int c = 0; c < 2; ++c) {
            const float v0 = acc[ot][nt][g * 4 + c * 2 + 0] + bb[g][c * 2 + 0];
            const float v1 = acc[ot][nt][g * 4 + c * 2 + 1] + bb[g][c * 2 + 1];
            const uint32_t cv = pkrtz(v0, v1);
            uint32_t r;
            asm("v_pk_max_f16 %0, %1, %2" : "=v"(r) : "v"(cv), "v"(0u));
            P[g][c] = r;
          }
        }
#pragma unroll
        for (int u = 0; u < 2; ++u) {
          uint32_t a0 = P[2 * u][0], b0v = P[2 * u + 1][0];
          uint32_t a1 = P[2 * u][1], b1v = P[2 * u + 1][1];
          asm("v_permlane32_swap_b32 %0, %1" : "+v"(a0), "+v"(b0v));
          asm("v_permlane32_swap_b32 %0, %1" : "+v"(a1), "+v"(b1v));
          Frag nb;
          nb.w[0] = a0;   // h==0: own lo pair | h==1: partner's lo pair
          nb.w[1] = a1;
          nb.w[2] = b0v;  // h==0: partner's hi pair | h==1: own hi pair
          nb.w[3] = b1v;
          B[nt][ot * 2 + u] = nb;
        }
      }
    }
  };

  __asm__ volatile("s_waitcnt vmcnt(0)" ::: "memory");  // W1 + biases staged (this wave)
  __syncthreads();                                      // ... and all waves
  do_epilogue(0);

  // ---- 9 hidden layers ----
#pragma unroll 1
  for (int l = 1; l <= 9; ++l) {
    const int cur = (l - 1) & 1;
    const int nxt = l & 1;
    if (l < 9) {  // prefetch W[l+1] into the other buffer
      const unsigned char* src = (const unsigned char*)wfrag + (size_t)l * 32768;
#pragma unroll
      for (int i = 0; i < 8; ++i) {
        const int off = i * 4096 + t * 16;
        g2lds16(src + off, &ldsW[nxt][off]);
      }
    }
    const unsigned char* wl = &ldsW[cur][0];
#pragma unroll
    for (int kt = 0; kt < 8; ++kt) {
#pragma unroll
      for (int ot = 0; ot < 4; ++ot) {
        const f16x8 a = *(const f16x8*)(wl + ot * 8192 + kt * 1024 + lane * 16);
        if (kt == 0) {
          acc[ot][0] = __builtin_amdgcn_mfma_f32_32x32x16_f16(a, B[0][kt].v, fzero, 0, 0, 0);
          acc[ot][1] = __builtin_amdgcn_mfma_f32_32x32x16_f16(a, B[1][kt].v, fzero, 0, 0, 0);
        } else {
          acc[ot][0] = __builtin_amdgcn_mfma_f32_32x32x16_f16(a, B[0][kt].v, acc[ot][0], 0, 0, 0);
          acc[ot][1] = __builtin_amdgcn_mfma_f32_32x32x16_f16(a, B[1][kt].v, acc[ot][1], 0, 0, 0);
        }
      }
    }
    do_epilogue(l);
    if (l < 9) {
      __asm__ volatile("s_waitcnt vmcnt(0)" ::: "memory");
      __syncthreads();
    }
  }

  // ---- output layer: MFMA with masked Wout A-fragment (row 0 only) ----
  // D row 0 lives in reg 0 of lanes 0..31 -> no shuffle reduce needed.
  {
    const float boutv = *boutp;
    f32x16 accO0 = fzero, accO1 = fzero;
#pragma unroll
    for (int kt = 0; kt < 8; ++kt) {
      const f16x8 wa = *(const f16x8*)(woutf16 + kt * 512 + lane * 8);
      accO0 = __builtin_amdgcn_mfma_f32_32x32x16_f16(wa, B[0][kt].v, accO0, 0, 0, 0);
      accO1 = __builtin_amdgcn_mfma_f32_32x32x16_f16(wa, B[1][kt].v, accO1, 0, 0, 0);
    }
    if (h == 0) {
      out[rowbase + ln]      = accO0[0] + boutv;
      out[rowbase + 32 + ln] = accO1[0] + boutv;
    }
  }
}

extern "C" void kernel_launch(void* const* d_in, const int* in_sizes, int n_in,
                              void* d_out, int out_size, void* d_ws, size_t ws_size,
                              hipStream_t stream) {
  (void)n_in; (void)out_size; (void)ws_size;  // needs ~313 KB of ws
  const float* x    = (const float*)d_in[0];
  const float* W0   = (const float*)d_in[1];
  const float* b0   = (const float*)d_in[2];
  const float* Wh   = (const float*)d_in[3];
  const float* bh   = (const float*)d_in[4];
  const float* Wout = (const float*)d_in[5];
  const float* bout = (const float*)d_in[6];
  float* out = (float*)d_out;

  char* ws = (char*)d_ws;
  _Float16* wfrag   = (_Float16*)(ws);
  _Float16* w0frag  = (_Float16*)(ws + 294912);
  float*    biasws  = (float*)(ws + 299008);
  _Float16* woutf16 = (_Float16*)(ws + 304128);

  const int n = in_sizes[0] / 4;  // 1048576 points

  prep_kernel<<<dim3(160), dim3(256), 0, stream>>>(W0, b0, Wh, bh, Wout,
                                                   wfrag, w0frag, biasws, woutf16);
  mlp_fused<<<dim3(n / 256), dim3(256), 0, stream>>>(x, wfrag, w0frag, biasws,
                                                     woutf16, bout, out);
}

// Round 5
// 261.172 us; speedup vs baseline: 1.3888x; 1.0738x over previous
//
#include <hip/hip_runtime.h>
#include <stdint.h>

// ---------------- types ----------------
typedef _Float16 f16x8 __attribute__((ext_vector_type(8)));
typedef __fp16   fp16x2 __attribute__((ext_vector_type(2)));
typedef float    f32x16 __attribute__((ext_vector_type(16)));

union Frag {
  f16x8    v;
  uint32_t w[4];
  _Float16 h[8];
};

union CVec {
  float4 q[4];
  f32x16 v;
};

__device__ __forceinline__ uint32_t pack2h(float a, float b) {
  union { _Float16 h[2]; uint32_t u; } r;
  r.h[0] = (_Float16)a;   // RNE f32->f16
  r.h[1] = (_Float16)b;
  return r.u;
}

__device__ __forceinline__ uint32_t pkrtz(float a, float b) {
  union { fp16x2 h2; uint32_t u; } cv;
  cv.h2 = __builtin_amdgcn_cvt_pkrtz(a, b);
  return cv.u;
}

__device__ __forceinline__ void g2lds16(const void* g, void* l) {
  __builtin_amdgcn_global_load_lds(
      (const __attribute__((address_space(1))) uint32_t*)g,
      (__attribute__((address_space(3))) uint32_t*)l, 16, 0, 0);
}

// ---------------- prep: fragment-order the weights (f16) ----------------
// ws layout (bytes):
//   wfrag   @ 0      : [9][4 ot][8 kt][64 lane][8 j] f16  = 294912 B
//   w0frag  @ 294912 : [4 ot][64 lane][8 j]          f16  = 4096 B   (K padded 4->16)
//   biasC   @ 299008 : [10 l][4 ot][2 h][16 r]       f32  = 5120 B   (MFMA C-operand order)
//   woutf16 @ 304128 : [8 kt][64 lane][8 j]          f16  = 8192 B   (A-frag, rows!=0 zeroed)
// fragment value convention (32x32x16 f16 MFMA):
//   A lane l holds row i = l&31, k = (l>>5)*8 + j
//   B lane l holds col j = l&31, k = (l>>5)*8 + j
//   D/C lane l holds col = l&31, row = (r&3) + 8*(r>>2) + 4*(l>>5)
__global__ void prep_kernel(const float* __restrict__ W0, const float* __restrict__ b0,
                            const float* __restrict__ Wh, const float* __restrict__ bh,
                            const float* __restrict__ Wout,
                            _Float16* __restrict__ wfrag, _Float16* __restrict__ w0frag,
                            float* __restrict__ biasC, _Float16* __restrict__ woutf16) {
  const int stride = gridDim.x * blockDim.x;
  for (int idx = blockIdx.x * blockDim.x + threadIdx.x; idx < 154880; idx += stride) {
    if (idx < 147456) {                       // wfrag: Wh[l][o][k] -> A-fragment order
      const int j = idx & 7, lane = (idx >> 3) & 63, kt = (idx >> 9) & 7,
                ot = (idx >> 12) & 3, l = idx >> 14;
      const int o = ot * 32 + (lane & 31);
      const int k = kt * 16 + (lane >> 5) * 8 + j;
      wfrag[idx] = (_Float16)Wh[(l * 128 + o) * 128 + k];
    } else if (idx < 147456 + 2048) {         // w0frag (K padded with zeros)
      const int i = idx - 147456;
      const int j = i & 7, lane = (i >> 3) & 63, ot = i >> 9;
      const int o = ot * 32 + (lane & 31);
      const int k = (lane >> 5) * 8 + j;
      w0frag[i] = (_Float16)(k < 4 ? W0[o * 4 + k] : 0.0f);
    } else if (idx < 147456 + 2048 + 1280) {  // biasC: C-operand order per (l,ot,h)
      const int i = idx - (147456 + 2048);
      const int r = i & 15, hh = (i >> 4) & 1, ot = (i >> 5) & 3, l = i >> 7;
      const int row = (r & 3) + 8 * (r >> 2) + 4 * hh;
      const int o = ot * 32 + row;
      biasC[i] = (l == 0) ? b0[o] : bh[(l - 1) * 128 + o];
    } else {                                  // Wout as masked A-fragment (row 0 only), f16
      const int i = idx - (147456 + 2048 + 1280);
      const int j = i & 7, lane = (i >> 3) & 63, kt = i >> 9;
      const int k = kt * 16 + (lane >> 5) * 8 + j;
      woutf16[i] = ((lane & 31) == 0) ? (_Float16)Wout[k] : (_Float16)0.0f;
    }
  }
}

// ---------------- fused MLP ----------------
__global__ __launch_bounds__(256, 2) void mlp_fused(
    const float* __restrict__ x,
    const _Float16* __restrict__ wfrag,
    const _Float16* __restrict__ w0frag,
    const float* __restrict__ biasCg,
    const _Float16* __restrict__ woutf16,
    const float* __restrict__ boutp,
    float* __restrict__ out) {
  // 2 x 32 KB W double-buffer + bias C-table; 70.7 KB -> 2 blocks/CU
  __shared__ __align__(16) unsigned char ldsW[2][32768];
  __shared__ __align__(16) float ldsBiasC[1280];

  const int t    = threadIdx.x;
  const int lane = t & 63;
  const int wv   = t >> 6;
  const int h    = lane >> 5;   // half-wave
  const int ln   = lane & 31;
  const long rowbase = (long)blockIdx.x * 256 + wv * 64;  // + nt*32 + ln

  // ---- prologue staging: W[1] -> ldsW[0]; bias C-table -> ldsBiasC ----
  {
    const unsigned char* src = (const unsigned char*)wfrag;  // layer 1 at offset 0
#pragma unroll
    for (int i = 0; i < 8; ++i) {
      const int off = i * 4096 + t * 16;
      g2lds16(src + off, &ldsW[0][off]);
    }
    const unsigned char* bsrc = (const unsigned char*)biasCg;
    g2lds16(bsrc + t * 16, (unsigned char*)ldsBiasC + t * 16);            // chunks 0..255
    if (t < 64) g2lds16(bsrc + (256 + t) * 16, (unsigned char*)ldsBiasC + (256 + t) * 16);
  }

  Frag   B[2][8];      // current-layer input fragments (H^T), per nt / k-tile
  f32x16 acc[4][2];    // [o-tile][n-tile], D = H_out^T
  const f32x16 fzero = (f32x16)0.0f;

  // broadcast read of the per-(layer,ot,half) C-operand (bias pre-placed in D order)
  auto load_cvec = [&](int l, int ot) -> f32x16 {
    CVec cv;
    const float* p = ldsBiasC + ((l * 4 + ot) * 2 + h) * 16;
#pragma unroll
    for (int g = 0; g < 4; ++g) cv.q[g] = *(const float4*)(p + g * 4);
    return cv.v;
  };

  // x loads + pack can overlap the staging latency
  Frag xb[2];
#pragma unroll
  for (int nt = 0; nt < 2; ++nt) {
    float4 xv = make_float4(0.f, 0.f, 0.f, 0.f);
    if (h == 0) xv = *(const float4*)(x + (rowbase + nt * 32 + ln) * 4);
    xb[nt].w[0] = pack2h(xv.x, xv.y);
    xb[nt].w[1] = pack2h(xv.z, xv.w);
    xb[nt].w[2] = 0u;
    xb[nt].w[3] = 0u;
  }

  __syncthreads();  // staging drained (implicit vmcnt(0) lgkmcnt(0) before barrier)

  // ---- layer 0: K=16 zero-padded MFMA, C = bias ----
#pragma unroll
  for (int ot = 0; ot < 4; ++ot) {
    const f16x8 a0 = *(const f16x8*)(w0frag + ot * 512 + lane * 8);
    const f32x16 cvec = load_cvec(0, ot);
    acc[ot][0] = __builtin_amdgcn_mfma_f32_32x32x16_f16(a0, xb[0].v, cvec, 0, 0, 0);
    acc[ot][1] = __builtin_amdgcn_mfma_f32_32x32x16_f16(a0, xb[1].v, cvec, 0, 0, 0);
  }

  // epilogue: relu+pack (bias already in acc), exchange lane<->lane+32 halves via
  // v_permlane32_swap_b32 so each lane holds its row's k-slice in next-layer
  // B-fragment order. One swap yields BOTH w[lo] and w[hi].
  auto do_epilogue = [&]() {
#pragma unroll
    for (int ot = 0; ot < 4; ++ot) {
#pragma unroll
      for (int nt = 0; nt < 2; ++nt) {
        uint32_t P[4][2];
#pragma unroll
        for (int g = 0; g < 4; ++g) {
#pragma unroll
          for (int c = 0; c < 2; ++c) {
            const uint32_t cv = pkrtz(acc[ot][nt][g * 4 + c * 2 + 0],
                                      acc[ot][nt][g * 4 + c * 2 + 1]);
            uint32_t r;
            asm("v_pk_max_f16 %0, %1, %2" : "=v"(r) : "v"(cv), "v"(0u));
            P[g][c] = r;
          }
        }
#pragma unroll
        for (int u = 0; u < 2; ++u) {
          uint32_t a0 = P[2 * u][0], b0v = P[2 * u + 1][0];
          uint32_t a1 = P[2 * u][1], b1v = P[2 * u + 1][1];
          asm("v_permlane32_swap_b32 %0, %1" : "+v"(a0), "+v"(b0v));
          asm("v_permlane32_swap_b32 %0, %1" : "+v"(a1), "+v"(b1v));
          Frag nb;
          nb.w[0] = a0;   // h==0: own lo pair | h==1: partner's lo pair
          nb.w[1] = a1;
          nb.w[2] = b0v;  // h==0: partner's hi pair | h==1: own hi pair
          nb.w[3] = b1v;
          B[nt][ot * 2 + u] = nb;
        }
      }
    }
  };

  do_epilogue();

  // ---- 9 hidden layers ----
#pragma unroll 1
  for (int l = 1; l <= 9; ++l) {
    const int cur = (l - 1) & 1;
    const int nxt = l & 1;
    if (l < 9) {  // prefetch W[l+1] into the other buffer (overlaps MFMA phase)
      const unsigned char* src = (const unsigned char*)wfrag + (size_t)l * 32768;
#pragma unroll
      for (int i = 0; i < 8; ++i) {
        const int off = i * 4096 + t * 16;
        g2lds16(src + off, &ldsW[nxt][off]);
      }
    }
    const unsigned char* wl = &ldsW[cur][0];
    __builtin_amdgcn_s_setprio(1);
#pragma unroll
    for (int kt = 0; kt < 8; ++kt) {
#pragma unroll
      for (int ot = 0; ot < 4; ++ot) {
        const f16x8 a = *(const f16x8*)(wl + ot * 8192 + kt * 1024 + lane * 16);
        if (kt == 0) {
          const f32x16 cvec = load_cvec(l, ot);
          acc[ot][0] = __builtin_amdgcn_mfma_f32_32x32x16_f16(a, B[0][kt].v, cvec, 0, 0, 0);
          acc[ot][1] = __builtin_amdgcn_mfma_f32_32x32x16_f16(a, B[1][kt].v, cvec, 0, 0, 0);
        } else {
          acc[ot][0] = __builtin_amdgcn_mfma_f32_32x32x16_f16(a, B[0][kt].v, acc[ot][0], 0, 0, 0);
          acc[ot][1] = __builtin_amdgcn_mfma_f32_32x32x16_f16(a, B[1][kt].v, acc[ot][1], 0, 0, 0);
        }
      }
    }
    __builtin_amdgcn_s_setprio(0);
    do_epilogue();
    if (l < 9) {
      __syncthreads();  // implicit full waitcnt drains the prefetch
    }
  }

  // ---- output layer: MFMA with masked Wout A-fragment (row 0 only) ----
  // D row 0 lives in reg 0 of lanes 0..31 -> no shuffle reduce needed.
  {
    const float boutv = *boutp;
    f32x16 accO0 = fzero, accO1 = fzero;
#pragma unroll
    for (int kt = 0; kt < 8; ++kt) {
      const f16x8 wa = *(const f16x8*)(woutf16 + kt * 512 + lane * 8);
      accO0 = __builtin_amdgcn_mfma_f32_32x32x16_f16(wa, B[0][kt].v, accO0, 0, 0, 0);
      accO1 = __builtin_amdgcn_mfma_f32_32x32x16_f16(wa, B[1][kt].v, accO1, 0, 0, 0);
    }
    if (h == 0) {
      out[rowbase + ln]      = accO0[0] + boutv;
      out[rowbase + 32 + ln] = accO1[0] + boutv;
    }
  }
}

extern "C" void kernel_launch(void* const* d_in, const int* in_sizes, int n_in,
                              void* d_out, int out_size, void* d_ws, size_t ws_size,
                              hipStream_t stream) {
  (void)n_in; (void)out_size; (void)ws_size;  // needs ~313 KB of ws
  const float* x    = (const float*)d_in[0];
  const float* W0   = (const float*)d_in[1];
  const float* b0   = (const float*)d_in[2];
  const float* Wh   = (const float*)d_in[3];
  const float* bh   = (const float*)d_in[4];
  const float* Wout = (const float*)d_in[5];
  const float* bout = (const float*)d_in[6];
  float* out = (float*)d_out;

  char* ws = (char*)d_ws;
  _Float16* wfrag   = (_Float16*)(ws);
  _Float16* w0frag  = (_Float16*)(ws + 294912);
  float*    biasC   = (float*)(ws + 299008);
  _Float16* woutf16 = (_Float16*)(ws + 304128);

  const int n = in_sizes[0] / 4;  // 1048576 points

  prep_kernel<<<dim3(160), dim3(256), 0, stream>>>(W0, b0, Wh, bh, Wout,
                                                   wfrag, w0frag, biasC, woutf16);
  mlp_fused<<<dim3(n / 256), dim3(256), 0, stream>>>(x, wfrag, w0frag, biasC,
                                                     woutf16, bout, out);
}

// Round 6
// 257.044 us; speedup vs baseline: 1.4111x; 1.0161x over previous
//
#include <hip/hip_runtime.h>
#include <stdint.h>

// ---------------- types ----------------
typedef _Float16 f16x8 __attribute__((ext_vector_type(8)));
typedef __fp16   fp16x2 __attribute__((ext_vector_type(2)));
typedef float    f32x16 __attribute__((ext_vector_type(16)));

union Frag {
  f16x8    v;
  uint32_t w[4];
  _Float16 h[8];
};

union CVec {
  float4 q[4];
  f32x16 v;
};

__device__ __forceinline__ uint32_t pack2h(float a, float b) {
  union { _Float16 h[2]; uint32_t u; } r;
  r.h[0] = (_Float16)a;   // RNE f32->f16
  r.h[1] = (_Float16)b;
  return r.u;
}

__device__ __forceinline__ uint32_t pkrtz(float a, float b) {
  union { fp16x2 h2; uint32_t u; } cv;
  cv.h2 = __builtin_amdgcn_cvt_pkrtz(a, b);
  return cv.u;
}

__device__ __forceinline__ void g2lds16(const void* g, void* l) {
  __builtin_amdgcn_global_load_lds(
      (const __attribute__((address_space(1))) uint32_t*)g,
      (__attribute__((address_space(3))) uint32_t*)l, 16, 0, 0);
}

// ---------------- prep: fragment-order the weights (f16) ----------------
// ws layout (bytes):
//   wfrag   @ 0      : [9][4 ot][8 kt][64 lane][8 j] f16  = 294912 B
//   w0frag  @ 294912 : [4 ot][64 lane][8 j]          f16  = 4096 B   (K padded 4->16)
//   biasC   @ 299008 : [10 l][4 ot][2 h][16 r]       f32  = 5120 B   (MFMA C-operand order)
//   woutf16 @ 304128 : [8 kt][64 lane][8 j]          f16  = 8192 B   (A-frag, rows!=0 zeroed)
// fragment value convention (32x32x16 f16 MFMA):
//   A lane l holds row i = l&31, k = (l>>5)*8 + j
//   B lane l holds col j = l&31, k = (l>>5)*8 + j
//   D/C lane l holds col = l&31, row = (r&3) + 8*(r>>2) + 4*(l>>5)
__global__ void prep_kernel(const float* __restrict__ W0, const float* __restrict__ b0,
                            const float* __restrict__ Wh, const float* __restrict__ bh,
                            const float* __restrict__ Wout,
                            _Float16* __restrict__ wfrag, _Float16* __restrict__ w0frag,
                            float* __restrict__ biasC, _Float16* __restrict__ woutf16) {
  const int stride = gridDim.x * blockDim.x;
  for (int idx = blockIdx.x * blockDim.x + threadIdx.x; idx < 154880; idx += stride) {
    if (idx < 147456) {                       // wfrag: Wh[l][o][k] -> A-fragment order
      const int j = idx & 7, lane = (idx >> 3) & 63, kt = (idx >> 9) & 7,
                ot = (idx >> 12) & 3, l = idx >> 14;
      const int o = ot * 32 + (lane & 31);
      const int k = kt * 16 + (lane >> 5) * 8 + j;
      wfrag[idx] = (_Float16)Wh[(l * 128 + o) * 128 + k];
    } else if (idx < 147456 + 2048) {         // w0frag (K padded with zeros)
      const int i = idx - 147456;
      const int j = i & 7, lane = (i >> 3) & 63, ot = i >> 9;
      const int o = ot * 32 + (lane & 31);
      const int k = (lane >> 5) * 8 + j;
      w0frag[i] = (_Float16)(k < 4 ? W0[o * 4 + k] : 0.0f);
    } else if (idx < 147456 + 2048 + 1280) {  // biasC: C-operand order per (l,ot,h)
      const int i = idx - (147456 + 2048);
      const int r = i & 15, hh = (i >> 4) & 1, ot = (i >> 5) & 3, l = i >> 7;
      const int row = (r & 3) + 8 * (r >> 2) + 4 * hh;
      const int o = ot * 32 + row;
      biasC[i] = (l == 0) ? b0[o] : bh[(l - 1) * 128 + o];
    } else {                                  // Wout as masked A-fragment (row 0 only), f16
      const int i = idx - (147456 + 2048 + 1280);
      const int j = i & 7, lane = (i >> 3) & 63, kt = i >> 9;
      const int k = kt * 16 + (lane >> 5) * 8 + j;
      woutf16[i] = ((lane & 31) == 0) ? (_Float16)Wout[k] : (_Float16)0.0f;
    }
  }
}

// ---------------- fused MLP ----------------
__global__ __launch_bounds__(256, 2) void mlp_fused(
    const float* __restrict__ x,
    const _Float16* __restrict__ wfrag,
    const _Float16* __restrict__ w0frag,
    const float* __restrict__ biasCg,
    const _Float16* __restrict__ woutf16,
    const float* __restrict__ boutp,
    float* __restrict__ out) {
  // 2 x 32 KB W double-buffer + bias C-table; 70.7 KB -> 2 blocks/CU
  __shared__ __align__(16) unsigned char ldsW[2][32768];
  __shared__ __align__(16) float ldsBiasC[1280];

  const int t    = threadIdx.x;
  const int lane = t & 63;
  const int wv   = t >> 6;
  const int h    = lane >> 5;   // half-wave
  const int ln   = lane & 31;
  const long rowbase = (long)blockIdx.x * 256 + wv * 64;  // + nt*32 + ln

  // ---- prologue staging: W[1] -> ldsW[0]; bias C-table ----
  {
    const unsigned char* src = (const unsigned char*)wfrag;  // layer 1 at offset 0
#pragma unroll
    for (int i = 0; i < 8; ++i) {
      const int off = i * 4096 + t * 16;
      g2lds16(src + off, &ldsW[0][off]);
    }
    const unsigned char* bsrc = (const unsigned char*)biasCg;
    g2lds16(bsrc + t * 16, (unsigned char*)ldsBiasC + t * 16);            // chunks 0..255
    if (t < 64) g2lds16(bsrc + (256 + t) * 16, (unsigned char*)ldsBiasC + (256 + t) * 16);
  }

  Frag   B[2][8];      // current-layer input fragments (H^T), per nt / k-tile
  f32x16 acc[4][2];    // [o-tile][n-tile], D = H_out^T
  const f32x16 fzero = (f32x16)0.0f;

  // broadcast read of the per-(layer,ot,half) C-operand (bias pre-placed in D order)
  auto load_cvec = [&](int l, int ot) -> f32x16 {
    CVec cv;
    const float* p = ldsBiasC + ((l * 4 + ot) * 2 + h) * 16;
#pragma unroll
    for (int g = 0; g < 4; ++g) cv.q[g] = *(const float4*)(p + g * 4);
    return cv.v;
  };

  // x loads + pack overlap the staging latency
  Frag xb[2];
#pragma unroll
  for (int nt = 0; nt < 2; ++nt) {
    float4 xv = make_float4(0.f, 0.f, 0.f, 0.f);
    if (h == 0) xv = *(const float4*)(x + (rowbase + nt * 32 + ln) * 4);
    xb[nt].w[0] = pack2h(xv.x, xv.y);
    xb[nt].w[1] = pack2h(xv.z, xv.w);
    xb[nt].w[2] = 0u;
    xb[nt].w[3] = 0u;
  }

  __syncthreads();  // staging drained (implicit vmcnt(0) lgkmcnt(0) before barrier)

  // ---- layer 0: K=16 zero-padded MFMA, C = bias ----
#pragma unroll
  for (int ot = 0; ot < 4; ++ot) {
    const f16x8 a0 = *(const f16x8*)(w0frag + ot * 512 + lane * 8);
    const f32x16 cvec = load_cvec(0, ot);
    acc[ot][0] = __builtin_amdgcn_mfma_f32_32x32x16_f16(a0, xb[0].v, cvec, 0, 0, 0);
    acc[ot][1] = __builtin_amdgcn_mfma_f32_32x32x16_f16(a0, xb[1].v, cvec, 0, 0, 0);
  }
  // NOTE: no barrier here — layer 1 reads ldsW[0], drained at the barrier above.

  // epilogue: relu+pack (bias already in acc), exchange lane<->lane+32 halves via
  // v_permlane32_swap_b32. One swap yields BOTH w[lo] and w[hi].
  auto do_epilogue = [&]() {
#pragma unroll
    for (int ot = 0; ot < 4; ++ot) {
#pragma unroll
      for (int nt = 0; nt < 2; ++nt) {
        uint32_t P[4][2];
#pragma unroll
        for (int g = 0; g < 4; ++g) {
#pragma unroll
          for (int c = 0; c < 2; ++c) {
            const uint32_t cv = pkrtz(acc[ot][nt][g * 4 + c * 2 + 0],
                                      acc[ot][nt][g * 4 + c * 2 + 1]);
            uint32_t r;
            asm("v_pk_max_f16 %0, %1, %2" : "=v"(r) : "v"(cv), "v"(0u));
            P[g][c] = r;
          }
        }
#pragma unroll
        for (int u = 0; u < 2; ++u) {
          uint32_t a0 = P[2 * u][0], b0v = P[2 * u + 1][0];
          uint32_t a1 = P[2 * u][1], b1v = P[2 * u + 1][1];
          asm("v_permlane32_swap_b32 %0, %1" : "+v"(a0), "+v"(b0v));
          asm("v_permlane32_swap_b32 %0, %1" : "+v"(a1), "+v"(b1v));
          Frag nb;
          nb.w[0] = a0;   // h==0: own lo pair | h==1: partner's lo pair
          nb.w[1] = a1;
          nb.w[2] = b0v;  // h==0: partner's hi pair | h==1: own hi pair
          nb.w[3] = b1v;
          B[nt][ot * 2 + u] = nb;
        }
      }
    }
  };

  // ---- rotated pipeline: R(l) = {prefetch W[l+1]; epilogue(l-1); MFMA(l); barrier} ----
  // Fully unrolled: static LDS addresses, one straight-line region per layer so the
  // scheduler can hide ds_reads + prefetch issue under epilogue VALU.
#pragma unroll
  for (int l = 1; l <= 9; ++l) {
    if (l < 9) {  // prefetch W[l+1] into buf[l&1] (last read by layer l-1, pre-barrier)
      const unsigned char* src = (const unsigned char*)wfrag + (size_t)l * 32768;
#pragma unroll
      for (int i = 0; i < 8; ++i) {
        const int off = i * 4096 + t * 16;
        g2lds16(src + off, &ldsW[l & 1][off]);
      }
    }
    do_epilogue();  // acc(l-1) -> B (register-only; overlaps loads below)
    const unsigned char* wl = &ldsW[(l - 1) & 1][0];
    __builtin_amdgcn_s_setprio(1);
#pragma unroll
    for (int kt = 0; kt < 8; ++kt) {
#pragma unroll
      for (int ot = 0; ot < 4; ++ot) {
        const f16x8 a = *(const f16x8*)(wl + ot * 8192 + kt * 1024 + lane * 16);
        if (kt == 0) {
          const f32x16 cvec = load_cvec(l, ot);
          acc[ot][0] = __builtin_amdgcn_mfma_f32_32x32x16_f16(a, B[0][kt].v, cvec, 0, 0, 0);
          acc[ot][1] = __builtin_amdgcn_mfma_f32_32x32x16_f16(a, B[1][kt].v, cvec, 0, 0, 0);
        } else {
          acc[ot][0] = __builtin_amdgcn_mfma_f32_32x32x16_f16(a, B[0][kt].v, acc[ot][0], 0, 0, 0);
          acc[ot][1] = __builtin_amdgcn_mfma_f32_32x32x16_f16(a, B[1][kt].v, acc[ot][1], 0, 0, 0);
        }
      }
    }
    __builtin_amdgcn_s_setprio(0);
    if (l < 9) __syncthreads();  // drains prefetch W[l+1]; gates buf reuse
  }

  // ---- output layer: MFMA with masked Wout A-fragment (row 0 only) ----
  // Pre-issue the 8 Wout fragment loads (global, L2-hot) before the last epilogue.
  {
    Frag wa[8];
#pragma unroll
    for (int kt = 0; kt < 8; ++kt)
      wa[kt].v = *(const f16x8*)(woutf16 + kt * 512 + lane * 8);
    const float boutv = *boutp;

    do_epilogue();  // layer 9 acc -> B

    f32x16 accO0 = fzero, accO1 = fzero;
#pragma unroll
    for (int kt = 0; kt < 8; ++kt) {
      accO0 = __builtin_amdgcn_mfma_f32_32x32x16_f16(wa[kt].v, B[0][kt].v, accO0, 0, 0, 0);
      accO1 = __builtin_amdgcn_mfma_f32_32x32x16_f16(wa[kt].v, B[1][kt].v, accO1, 0, 0, 0);
    }
    if (h == 0) {
      out[rowbase + ln]      = accO0[0] + boutv;
      out[rowbase + 32 + ln] = accO1[0] + boutv;
    }
  }
}

extern "C" void kernel_launch(void* const* d_in, const int* in_sizes, int n_in,
                              void* d_out, int out_size, void* d_ws, size_t ws_size,
                              hipStream_t stream) {
  (void)n_in; (void)out_size; (void)ws_size;  // needs ~313 KB of ws
  const float* x    = (const float*)d_in[0];
  const float* W0   = (const float*)d_in[1];
  const float* b0   = (const float*)d_in[2];
  const float* Wh   = (const float*)d_in[3];
  const float* bh   = (const float*)d_in[4];
  const float* Wout = (const float*)d_in[5];
  const float* bout = (const float*)d_in[6];
  float* out = (float*)d_out;

  char* ws = (char*)d_ws;
  _Float16* wfrag   = (_Float16*)(ws);
  _Float16* w0frag  = (_Float16*)(ws + 294912);
  float*    biasC   = (float*)(ws + 299008);
  _Float16* woutf16 = (_Float16*)(ws + 304128);

  const int n = in_sizes[0] / 4;  // 1048576 points

  prep_kernel<<<dim3(160), dim3(256), 0, stream>>>(W0, b0, Wh, bh, Wout,
                                                   wfrag, w0frag, biasC, woutf16);
  mlp_fused<<<dim3(n / 256), dim3(256), 0, stream>>>(x, wfrag, w0frag, biasC,
                                                     woutf16, bout, out);
}